// Round 1
// baseline (1203.107 us; speedup 1.0000x reference)
//
#include <hip/hip_runtime.h>
#include <cstdint>
#include <cstddef>

// ---------------- problem constants ----------------
#define TGT   24
#define BS    16
#define SRC   400
#define VOCABN 32000
#define DIM   256
#define NROW  (TGT*BS)   // 384

typedef __bf16 bf16_t;
typedef __bf16 v8bf __attribute__((ext_vector_type(8)));
typedef float  v4f  __attribute__((ext_vector_type(4)));

// ---------------- prep: dtype conversions / transposes / gather ----------------
__global__ void k_prep(const float* __restrict__ Whh, const float* __restrict__ Wad,
                       const float* __restrict__ he,  const float* __restrict__ Wemb,
                       const float* __restrict__ Wproj, const float* __restrict__ Wae,
                       const float* __restrict__ Wih, const int* __restrict__ inputs,
                       bf16_t* o_whh, bf16_t* o_wadT, bf16_t* o_he, bf16_t* o_wemb,
                       bf16_t* o_wprojT, bf16_t* o_wae, bf16_t* o_wih, bf16_t* o_embA)
{
    const long S0=262144, S1=65536, S2=1638400, S3=8192000, S4=196608, S5=65536, S6=262144, S7=98304;
    const long total = S0+S1+S2+S3+S4+S5+S6+S7;
    for (long i = (long)blockIdx.x*blockDim.x + threadIdx.x; i < total;
         i += (long)gridDim.x*blockDim.x) {
        long j = i;
        if (j < S0) { o_whh[j] = (bf16_t)Whh[j]; continue; }           j -= S0;
        if (j < S1) { long n = j>>8, k = j&255; o_wadT[j] = (bf16_t)Wad[k*DIM + n]; continue; } j -= S1;
        if (j < S2) { o_he[j] = (bf16_t)he[j]; continue; }             j -= S2;
        if (j < S3) { o_wemb[j] = (bf16_t)Wemb[j]; continue; }         j -= S3;
        if (j < S4) { long n = j>>8, k = j&255; o_wprojT[j] = (bf16_t)Wproj[k*768 + n]; continue; } j -= S4;
        if (j < S5) { o_wae[j] = (bf16_t)Wae[j]; continue; }           j -= S5;
        if (j < S6) { o_wih[j] = (bf16_t)Wih[j]; continue; }           j -= S6;
        { long r = j>>8, k = j&255; o_embA[j] = (bf16_t)Wemb[(long)inputs[r]*DIM + k]; }
    }
}

// ---------------- generic bf16 MFMA GEMM, 128x128 tile, BK=32 ----------------
// C[M,N] = A[M,K] @ B[N,K]^T   (both row-major, K-contiguous)
__global__ __launch_bounds__(256) void k_gemm(
    const bf16_t* __restrict__ A, const bf16_t* __restrict__ B,
    int M, int N, int K, int Ntiles, int mode,
    float* outF, bf16_t* outB,
    const float* __restrict__ bias0, const float* __restrict__ bias1,
    const int* __restrict__ padp)
{
    __shared__ bf16_t As[128*40];   // pitch 40 (pad 8) to break bank conflicts
    __shared__ bf16_t Bs[128*40];
    const int tid  = threadIdx.x;
    const int mt   = blockIdx.x / Ntiles, nt = blockIdx.x % Ntiles;
    const int m0   = mt*128, n0 = nt*128;
    const int lane = tid & 63, wave = tid >> 6;
    const int wm   = wave >> 1, wn = wave & 1;
    const int quad = lane >> 4, l16 = lane & 15;

    v4f acc[4][4];
#pragma unroll
    for (int i=0;i<4;i++)
#pragma unroll
        for (int j=0;j<4;j++) acc[i][j] = (v4f){0.f,0.f,0.f,0.f};

    const int srow = tid >> 1, shalf = tid & 1;       // staging: 2 threads/row
    const bf16_t* Ag = A + (long)(m0+srow)*K + shalf*16;
    const bf16_t* Bg = B + (long)(n0+srow)*K + shalf*16;
    bf16_t* AsW = &As[srow*40 + shalf*16];
    bf16_t* BsW = &Bs[srow*40 + shalf*16];

    for (int kc = 0; kc < K; kc += 32) {
        __syncthreads();
        uint4 a0 = *(const uint4*)(Ag + kc);
        uint4 a1 = *(const uint4*)(Ag + kc + 8);
        uint4 b0 = *(const uint4*)(Bg + kc);
        uint4 b1 = *(const uint4*)(Bg + kc + 8);
        *(uint4*)AsW = a0; *(uint4*)(AsW+8) = a1;
        *(uint4*)BsW = b0; *(uint4*)(BsW+8) = b1;
        __syncthreads();
        v8bf af[4], bb[4];
#pragma unroll
        for (int i=0;i<4;i++) {
            af[i] = *(const v8bf*)&As[(wm*64 + i*16 + l16)*40 + quad*8];
            bb[i] = *(const v8bf*)&Bs[(wn*64 + i*16 + l16)*40 + quad*8];
        }
#pragma unroll
        for (int i=0;i<4;i++)
#pragma unroll
            for (int j=0;j<4;j++)
                acc[i][j] = __builtin_amdgcn_mfma_f32_16x16x32_bf16(af[i], bb[j], acc[i][j], 0,0,0);
    }

    const int pad = padp ? *padp : -1;
#pragma unroll
    for (int i=0;i<4;i++) {
#pragma unroll
        for (int j=0;j<4;j++) {
#pragma unroll
            for (int r=0;r<4;r++) {
                const int gr = m0 + wm*64 + i*16 + quad*4 + r;   // C/D row = quad*4+reg
                const int gc = n0 + wn*64 + j*16 + l16;          // C/D col = lane&15
                const float v = acc[i][j][r];
                if (mode == 0)      outF[(long)gr*N + gc] = v + bias0[gc] + bias1[gc];
                else if (mode == 1) outB[(long)gr*N + gc] = (bf16_t)tanhf(v);
                else if (mode == 2) outB[(long)gr*N + gc] = (bf16_t)v;
                else {
                    float ex = (gc == pad) ? 0.f : __expf(v + bias0[gc]);
                    outF[(long)gr*N + gc] = ex;
                }
            }
        }
    }
}

// ---------------- sequential decoder recurrence: one block per batch elem ----------------
__global__ __launch_bounds__(512) void k_rec(
    const bf16_t* __restrict__ Whh,  const bf16_t* __restrict__ WadT,
    const bf16_t* __restrict__ he,   const bf16_t* __restrict__ ke,
    const float*  __restrict__ xg,
    const float*  __restrict__ h0,   const float* __restrict__ c0,
    const float*  __restrict__ wu,   const float* __restrict__ bu,
    bf16_t* __restrict__ feat, float* __restrict__ Ae, float* __restrict__ ps)
{
    __shared__ float h[DIM], cc[DIM], qd[DIM], gates[4*DIM];
    __shared__ float hist[TGT][DIM+1];     // +1 pad: intra-attn reads column-wise
    __shared__ float ee[SRC], Ehist[SRC];
    __shared__ float ad[TGT+1];
    __shared__ float cpart[2][DIM];
    __shared__ float red[8];
    __shared__ float esum_s, edinv_s;

    const int b = blockIdx.x;
    const int t = threadIdx.x;
    if (t < DIM) { h[t] = h0[b*DIM + t]; cc[t] = c0[b*DIM + t]; }
    __syncthreads();

    for (int step = 0; step < TGT; ++step) {
        // -- gates = xg + h @ Whh^T  (k split 4-ways per row) --
        {
            const int jj = t >> 2, kq = (t & 3) * 64;
#pragma unroll 1
            for (int pass = 0; pass < 8; ++pass) {
                const int j = pass*128 + jj;
                const uint4* wrow = (const uint4*)(Whh + (long)j*DIM + kq);
                float p = 0.f;
#pragma unroll
                for (int m=0;m<8;m++) {
                    v8bf w = __builtin_bit_cast(v8bf, wrow[m]);
#pragma unroll
                    for (int i=0;i<8;i++) p += (float)w[i] * h[kq + m*8 + i];
                }
                p += __shfl_down(p, 1);
                p += __shfl_down(p, 2);
                if ((t & 3) == 0) gates[j] = p + xg[((long)step*BS + b)*1024 + j];
            }
        }
        __syncthreads();
        // -- LSTM cell --
        if (t < DIM) {
            const float gi = gates[t], gf = gates[DIM+t], gg = gates[2*DIM+t], go = gates[3*DIM+t];
            const float si = 1.f/(1.f+__expf(-gi));
            const float sf = 1.f/(1.f+__expf(-gf));
            const float so = 1.f/(1.f+__expf(-go));
            const float cn = sf*cc[t] + si*tanhf(gg);
            const float hn = so*tanhf(cn);
            cc[t] = cn; h[t] = hn; hist[step][t] = hn;
        }
        __syncthreads();
        // -- qd[n] = sum_k h[k] * WadT[n][k] --
        {
            const int jj = t >> 2, kq = (t & 3) * 64;
#pragma unroll 1
            for (int pass = 0; pass < 2; ++pass) {
                const int n = pass*128 + jj;
                const uint4* wrow = (const uint4*)(WadT + (long)n*DIM + kq);
                float p = 0.f;
#pragma unroll
                for (int m=0;m<8;m++) {
                    v8bf w = __builtin_bit_cast(v8bf, wrow[m]);
#pragma unroll
                    for (int i=0;i<8;i++) p += (float)w[i] * h[kq + m*8 + i];
                }
                p += __shfl_down(p, 1);
                p += __shfl_down(p, 2);
                if ((t & 3) == 0) qd[n] = p;
            }
        }
        // -- encoder attention scores (W_ae pre-folded into ke) + cumulative-exp trick --
        if (t < SRC) {
            const uint4* krow = (const uint4*)(ke + ((long)t*BS + b)*DIM);
            float e = 0.f;
#pragma unroll 8
            for (int m=0;m<32;m++) {
                v8bf w = __builtin_bit_cast(v8bf, krow[m]);
#pragma unroll
                for (int i=0;i<8;i++) e += (float)w[i] * h[m*8+i];
            }
            const float ex = __expf(e);
            float v;
            if (step == 0) { v = ex; Ehist[t] = ex; }
            else           { v = ex / Ehist[t]; Ehist[t] += ex; }
            ee[t] = v;
        }
        __syncthreads();
        // -- sum(ee) --
        {
            float p = (t < SRC) ? ee[t] : 0.f;
#pragma unroll
            for (int o=32;o>0;o>>=1) p += __shfl_down(p, o);
            if ((t & 63) == 0) red[t>>6] = p;
            __syncthreads();
            if (t == 0) { float s=0.f; for (int i=0;i<8;i++) s+=red[i]; esum_s = s; }
            __syncthreads();
        }
        const float inv_es = 1.f / esum_s;
        if (t < SRC) Ae[((long)step*BS + b)*SRC + t] = ee[t] * inv_es;
        // -- c_e numerator, s-range split in half across 512 threads --
        {
            const int d = t & 255, hf = t >> 8;
            float p = 0.f;
            const int s0 = hf*200, s1 = s0+200;
            for (int s = s0; s < s1; ++s)
                p += ee[s] * (float)he[((long)s*BS + b)*DIM + d];
            cpart[hf][d] = p;
        }
        // -- intra-decoder attention scores --
        if (t <= step) {
            float e = 0.f;
            for (int d2=0; d2<DIM; ++d2) e += qd[d2]*hist[t][d2];
            ad[t] = __expf(e);
        }
        __syncthreads();
        if (t == 0) {
            float s = 0.f;
            for (int tau=0; tau<=step; ++tau) s += ad[tau];
            edinv_s = 1.f/s;
        }
        __syncthreads();
        // -- c_d, feat store, p_switch partial --
        float psw_part = 0.f;
        if (t < DIM) {
            const float ce = (cpart[0][t] + cpart[1][t]) * inv_es;
            float cd = 0.f;
            if (step > 0) {
                for (int tau=0; tau<=step; ++tau) cd += ad[tau]*hist[tau][t];
                cd *= edinv_s;
            }
            const long fr = ((long)step*BS + b)*768;
            const float hd = h[t];
            feat[fr + t]         = (bf16_t)hd;
            feat[fr + DIM + t]   = (bf16_t)ce;
            feat[fr + 2*DIM + t] = (bf16_t)cd;
            psw_part = hd*wu[t] + ce*wu[DIM+t] + cd*wu[2*DIM+t];
        }
        {
            float p = psw_part;
#pragma unroll
            for (int o=32;o>0;o>>=1) p += __shfl_down(p, o);
            if ((t & 63) == 0) red[t>>6] = p;
            __syncthreads();
            if (t == 0) {
                float s = 0.f; for (int i=0;i<8;i++) s += red[i];
                ps[step*BS + b] = 1.f/(1.f+__expf(-(s + bu[0])));
            }
        }
        __syncthreads();
    }
}

// ---------------- per-row softmax denominator -> scale = p_switch / sum ----------------
__global__ __launch_bounds__(256) void k_rowsum(const float* __restrict__ ex,
                                                const float* __restrict__ ps,
                                                float* __restrict__ scale)
{
    __shared__ float red[4];
    const int r = blockIdx.x;
    const float4* p = (const float4*)(ex + (long)r*VOCABN);
    float s = 0.f;
    for (int i = threadIdx.x; i < VOCABN/4; i += 256) {
        float4 v = p[i];
        s += v.x + v.y + v.z + v.w;
    }
#pragma unroll
    for (int o=32;o>0;o>>=1) s += __shfl_down(s, o);
    if ((threadIdx.x & 63) == 0) red[threadIdx.x>>6] = s;
    __syncthreads();
    if (threadIdx.x == 0) scale[r] = ps[r] / (red[0]+red[1]+red[2]+red[3]);
}

// ---------------- scores = exp_logits * scale[r] ----------------
__global__ void k_norm(float* __restrict__ out, const float* __restrict__ scale)
{
    const long n4 = (long)NROW*VOCABN/4;
    for (long i = (long)blockIdx.x*blockDim.x + threadIdx.x; i < n4;
         i += (long)gridDim.x*blockDim.x) {
        const long r = (i*4)/VOCABN;          // VOCABN % 4 == 0: no row straddle
        float4 v = ((float4*)out)[i];
        const float sc = scale[r];
        v.x*=sc; v.y*=sc; v.z*=sc; v.w*=sc;
        ((float4*)out)[i] = v;
    }
}

// ---------------- copy mechanism scatter: out[r, src[s,b]] += A_e * p_switch ----------------
__global__ __launch_bounds__(256) void k_copy(float* __restrict__ out,
                                              const int* __restrict__ src,
                                              const float* __restrict__ Ae,
                                              const float* __restrict__ ps)
{
    const int r = blockIdx.x;        // r = t*BS + b
    const int b = r & (BS-1);
    const float p = ps[r];
    for (int s = threadIdx.x; s < SRC; s += 256) {
        const int v = src[s*BS + b];
        atomicAdd(&out[(long)r*VOCABN + v], Ae[(long)r*SRC + s] * p);
    }
}

// ---------------- workspace layout (bytes, all 16B-aligned) ----------------
#define O_WHH    0u          // 524,288
#define O_WADT   524288u     // 131,072
#define O_HE     655360u     // 3,276,800
#define O_KE     3932160u    // 3,276,800
#define O_WEMB   7208960u    // 16,384,000
#define O_WPROJT 23592960u   // 393,216
#define O_WIH    23986176u   // 524,288
#define O_EMBA   24510464u   // 196,608
#define O_WOUT   24707072u   // 49,152,000
#define O_XG     73859072u   // 1,572,864
#define O_FEAT   75431936u   // 589,824
#define O_AE     76021760u   // 614,400
#define O_PS     76636160u   // 1,536
#define O_SCALE  76637696u   // 1,536
#define O_WAE    76639232u   // 131,072   (W_ae bf16)
// total: 76,770,304 bytes

extern "C" void kernel_launch(void* const* d_in, const int* in_sizes, int n_in,
                              void* d_out, int out_size, void* d_ws, size_t ws_size,
                              hipStream_t stream)
{
    const int*   inputs = (const int*)  d_in[0];
    const int*   src    = (const int*)  d_in[1];
    const float* h_e    = (const float*)d_in[2];
    const float* h0     = (const float*)d_in[3];
    const float* c0     = (const float*)d_in[4];
    const float* W_emb  = (const float*)d_in[5];
    const float* W_ih   = (const float*)d_in[6];
    const float* b_ih   = (const float*)d_in[7];
    const float* W_hh   = (const float*)d_in[8];
    const float* b_hh   = (const float*)d_in[9];
    const float* W_ae   = (const float*)d_in[10];
    const float* W_ad   = (const float*)d_in[11];
    const float* W_proj = (const float*)d_in[12];
    const float* W_u    = (const float*)d_in[13];
    const float* b_u    = (const float*)d_in[14];
    const float* b_out  = (const float*)d_in[15];
    const int*   pad_id = (const int*)  d_in[16];

    char* w = (char*)d_ws;
    bf16_t* whh_bf  = (bf16_t*)(w + O_WHH);
    bf16_t* wadT_bf = (bf16_t*)(w + O_WADT);
    bf16_t* he_bf   = (bf16_t*)(w + O_HE);
    bf16_t* ke_bf   = (bf16_t*)(w + O_KE);
    bf16_t* wemb_bf = (bf16_t*)(w + O_WEMB);
    bf16_t* wprojT  = (bf16_t*)(w + O_WPROJT);
    bf16_t* wih_bf  = (bf16_t*)(w + O_WIH);
    bf16_t* embA_bf = (bf16_t*)(w + O_EMBA);
    bf16_t* wout_bf = (bf16_t*)(w + O_WOUT);
    float*  xg      = (float*) (w + O_XG);
    bf16_t* feat_bf = (bf16_t*)(w + O_FEAT);
    float*  Ae      = (float*) (w + O_AE);
    float*  ps      = (float*) (w + O_PS);
    float*  scale   = (float*) (w + O_SCALE);
    bf16_t* wae_bf  = (bf16_t*)(w + O_WAE);
    float*  out     = (float*)d_out;

    k_prep<<<1024, 256, 0, stream>>>(W_hh, W_ad, h_e, W_emb, W_proj, W_ae, W_ih, inputs,
                                     whh_bf, wadT_bf, he_bf, wemb_bf, wprojT,
                                     wae_bf, wih_bf, embA_bf);
    // xg = embA @ W_ih^T + b_ih + b_hh        (M=384,  N=1024, K=256)
    k_gemm<<<3*8, 256, 0, stream>>>(embA_bf, wih_bf, NROW, 1024, 256, 8, 0,
                                    xg, nullptr, b_ih, b_hh, nullptr);
    // ke = h_e @ W_ae^T                        (M=6400, N=256,  K=256)
    k_gemm<<<50*2, 256, 0, stream>>>(he_bf, wae_bf, 6400, 256, 256, 2, 2,
                                     nullptr, ke_bf, nullptr, nullptr, nullptr);
    // W_out = tanh(W_emb @ W_proj)             (M=32000, N=768, K=256)
    k_gemm<<<250*6, 256, 0, stream>>>(wemb_bf, wprojT, VOCABN, 768, 256, 6, 1,
                                      nullptr, wout_bf, nullptr, nullptr, nullptr);
    // sequential decoder recurrence
    k_rec<<<BS, 512, 0, stream>>>(whh_bf, wadT_bf, he_bf, ke_bf, xg, h0, c0, W_u, b_u,
                                  feat_bf, Ae, ps);
    // exp(logits + b_out), pad -> 0            (M=384, N=32000, K=768) -> d_out
    k_gemm<<<3*250, 256, 0, stream>>>(feat_bf, wout_bf, NROW, VOCABN, 768, 250, 3,
                                      out, nullptr, b_out, nullptr, pad_id);
    k_rowsum<<<NROW, 256, 0, stream>>>(out, ps, scale);
    k_norm<<<2048, 256, 0, stream>>>(out, scale);
    k_copy<<<NROW, 256, 0, stream>>>(out, src, Ae, ps);
}